// Round 8
// baseline (789.797 us; speedup 1.0000x reference)
//
#include <hip/hip_runtime.h>

// Problem constants
#define Sdim   2048
#define Hdim   4096
#define NHEADS 32
#define Dh     128
#define Mrows  4096      // B*S
#define QKVLD  12288     // 3*H

typedef __attribute__((ext_vector_type(8))) short short8;
typedef __attribute__((ext_vector_type(4))) float f32x4;
typedef __attribute__((ext_vector_type(4))) float float4v;

__device__ __forceinline__ short f2bf(float f) {
  union { float f; unsigned u; } x; x.f = f;
  unsigned r = x.u + 0x7fffu + ((x.u >> 16) & 1u);  // RNE
  return (short)(r >> 16);
}
__device__ __forceinline__ float bf2f(short s) {
  union { unsigned u; float f; } x; x.u = ((unsigned)(unsigned short)s) << 16;
  return x.f;
}

__device__ __forceinline__ void gload_lds16(const void* g, void* l) {
  __builtin_amdgcn_global_load_lds(
      (const __attribute__((address_space(1))) void*)g,
      (__attribute__((address_space(3))) void*)l, 16, 0, 0);
}

// ---------------- fp32 -> bf16 convert (8 elems/thread) ----------------
__global__ void k_cvt(const float* __restrict__ src, short* __restrict__ dst, int n8) {
  int idx = blockIdx.x * blockDim.x + threadIdx.x;
  if (idx >= n8) return;
  const float4v* s = (const float4v*)src + (size_t)idx * 2;
  float4v a = s[0], b = s[1];
  short8 o;
  o[0] = f2bf(a.x); o[1] = f2bf(a.y); o[2] = f2bf(a.z); o[3] = f2bf(a.w);
  o[4] = f2bf(b.x); o[5] = f2bf(b.y); o[6] = f2bf(b.z); o[7] = f2bf(b.w);
  *((short8*)dst + idx) = o;
}

// ---- transpose + convert, vectorized both sides: dst[C][R] bf16 = src[R][C] f32 ----
__global__ void k_tcvt64(const float* __restrict__ src, short* __restrict__ dst,
                         int R, int C) {
  __shared__ float t[64][65];
  const int tid = threadIdx.x;          // 256
  const int r0 = blockIdx.y * 64, c0 = blockIdx.x * 64;
  const int ir = tid >> 4, ic = (tid & 15) << 2;
#pragma unroll
  for (int p = 0; p < 4; ++p) {
    const float4v v = *(const float4v*)(src + (size_t)(r0 + p * 16 + ir) * C + c0 + ic);
    t[p * 16 + ir][ic] = v.x; t[p * 16 + ir][ic + 1] = v.y;
    t[p * 16 + ir][ic + 2] = v.z; t[p * 16 + ir][ic + 3] = v.w;
  }
  __syncthreads();
  const int oc = tid >> 3, orr = (tid & 7) << 3;
#pragma unroll
  for (int p = 0; p < 2; ++p) {
    int c = p * 32 + oc;
    short8 o;
#pragma unroll
    for (int j = 0; j < 8; ++j) o[j] = f2bf(t[orr + j][c]);
    *(short8*)(dst + (size_t)(c0 + c) * R + r0 + orr) = o;
  }
}

// ============ 256x256-tile bf16 GEMM, 8 waves, 4 phases/K-tile, counted vmcnt ============
// MODE 0: plain fp32 direct store (out = O @ w_o).
// MODE 1: fused epilogue for qkv: restage C-tile in LDS (chunk-XOR swizzled), apply RoPE
//         to q/k column-blocks (block-uniform), wide short8 stores; V blocks additionally
//         emit V^T directly (kills the separate k_rope8 and k_vt kernels).
__device__ __forceinline__ void stage_half256(const short* G, int ld, int row0, int kcol,
                                              char* lds, int tid) {
#pragma unroll
  for (int j = 0; j < 2; ++j) {
    int p = j * 512 + tid;            // 16B chunk id in [0,1024): 8 chunks per 64-col row
    int r = p >> 3;
    int c = ((p & 7) ^ (r & 7)) << 3; // swizzled source column (elements)
    gload_lds16(G + (size_t)(row0 + r) * ld + kcol + c,
                lds + ((j * 512 + (tid & 448)) << 4));
  }
}

#define MFMA_Q(qm, qn)                                                                   \
  do {                                                                                   \
    __builtin_amdgcn_s_setprio(1);                                                       \
    _Pragma("unroll")                                                                    \
    for (int m4 = 0; m4 < 4; ++m4)                                                       \
      _Pragma("unroll")                                                                  \
      for (int n2 = 0; n2 < 2; ++n2) {                                                   \
        acc[(qm)*4+m4][(qn)*2+n2] = __builtin_amdgcn_mfma_f32_16x16x32_bf16(             \
            av[m4][0], bv[(qn)*2+n2][0], acc[(qm)*4+m4][(qn)*2+n2], 0, 0, 0);            \
        acc[(qm)*4+m4][(qn)*2+n2] = __builtin_amdgcn_mfma_f32_16x16x32_bf16(             \
            av[m4][1], bv[(qn)*2+n2][1], acc[(qm)*4+m4][(qn)*2+n2], 0, 0, 0);            \
      }                                                                                  \
    __builtin_amdgcn_s_setprio(0);                                                       \
  } while (0)

#define PH_BARRIER()                    \
  do {                                  \
    __builtin_amdgcn_s_barrier();       \
    __builtin_amdgcn_sched_barrier(0);  \
  } while (0)

// swizzled byte address within the epilogue C-tile LDS [256 rows][256 cols] bf16
__device__ __forceinline__ int ct_addr(int row, int col) {
  return row * 512 + ((((col >> 3) ^ ((row >> 3) & 7)) << 4) | ((col & 7) << 1));
}

template<int MODE>
__global__ __launch_bounds__(512, 2) void k_gemm256(const short* __restrict__ A, int lda,
                                                    const short* __restrict__ Bt, int ldb,
                                                    void* __restrict__ Cp, int ldc,
                                                    int Ndim, int Kdim,
                                                    const int* __restrict__ positions,
                                                    short* __restrict__ Vtg) {
  __shared__ __align__(16) char smem[131072];
  const int tid  = threadIdx.x;
  const int lane = tid & 63;
  const int wave = tid >> 6;
  const int lo = lane & 15, hi = lane >> 4;
  const int wr = wave >> 2, wc = wave & 3;   // 2M x 4N waves; per-wave out 128x64

  // T1: XCD-aware bijective block swizzle (grid % 8 == 0 for all our calls)
  const int nblk = gridDim.x;
  const int lid = (blockIdx.x & 7) * (nblk >> 3) + (blockIdx.x >> 3);
  const int nbn = Ndim >> 8;
  const int bm0 = (lid / nbn) << 8;
  const int bn0 = (lid % nbn) << 8;

  f32x4 acc[8][4];
#pragma unroll
  for (int i = 0; i < 8; ++i)
#pragma unroll
    for (int j = 0; j < 4; ++j) acc[i][j] = (f32x4){0.f, 0.f, 0.f, 0.f};

  short8 av[4][2], bv[4][2];
  const int swz = (lo & 7) << 4;
  const int brow = (wc & 1) * 64;

  // prologue: K-tile 0 -> slot 0
  stage_half256(Bt, ldb, bn0,       0, smem + 32768,         tid);
  stage_half256(Bt, ldb, bn0 + 128, 0, smem + 32768 + 16384, tid);
  stage_half256(A,  lda, bm0,       0, smem,                 tid);
  stage_half256(A,  lda, bm0 + 128, 0, smem + 16384,         tid);

  const int NK = Kdim >> 6;
  for (int kt = 0; kt < NK; ++kt) {
    const int cur = kt & 1;
    const char* Ab = smem + cur * 65536 + wr * 16384;                 // wave's A half
    const char* Bb = smem + cur * 65536 + 32768 + (wc >> 1) * 16384;  // wave's B half
    char* nA = smem + (cur ^ 1) * 65536;
    char* nB = nA + 32768;
    const int kc = (kt + 1) << 6;
    const bool pf = (kt + 1 < NK);

    // ---- phase 0: stage B'h0+B'h1; counted drain; read A[0-3],B[0-1]; MFMA (0,0) ----
    if (pf) {
      stage_half256(Bt, ldb, bn0,       kc, nB,         tid);
      stage_half256(Bt, ldb, bn0 + 128, kc, nB + 16384, tid);
      asm volatile("s_waitcnt vmcnt(4)" ::: "memory");   // prev 8 landed; own 4 in flight
    } else {
      asm volatile("s_waitcnt vmcnt(0)" ::: "memory");   // final tile: full drain
    }
    PH_BARRIER();   // after this, slot cur is fully landed for ALL waves
#pragma unroll
    for (int m4 = 0; m4 < 4; ++m4)
#pragma unroll
      for (int ks = 0; ks < 2; ++ks)
        av[m4][ks] = *(const short8*)(Ab + (m4 * 16 + lo) * 128 + ((ks * 64 + hi * 16) ^ swz));
#pragma unroll
    for (int ni = 0; ni < 2; ++ni)
#pragma unroll
      for (int ks = 0; ks < 2; ++ks)
        bv[ni][ks] = *(const short8*)(Bb + (brow + ni * 16 + lo) * 128 + ((ks * 64 + hi * 16) ^ swz));
    MFMA_Q(0, 0);
    // hoisted reads for phase 1 (slot cur is landed)
#pragma unroll
    for (int ni = 2; ni < 4; ++ni)
#pragma unroll
      for (int ks = 0; ks < 2; ++ks)
        bv[ni][ks] = *(const short8*)(Bb + (brow + ni * 16 + lo) * 128 + ((ks * 64 + hi * 16) ^ swz));

    // ---- phase 1: stage A'h0+A'h1; MFMA (0,1); hoist A-rows 64-127 reads ----
    if (pf) {
      stage_half256(A, lda, bm0,       kc, nA,         tid);
      stage_half256(A, lda, bm0 + 128, kc, nA + 16384, tid);
    }
    PH_BARRIER();
    MFMA_Q(0, 1);
#pragma unroll
    for (int m4 = 0; m4 < 4; ++m4)
#pragma unroll
      for (int ks = 0; ks < 2; ++ks)
        av[m4][ks] = *(const short8*)(Ab + ((64 + m4 * 16 + lo) * 128) + ((ks * 64 + hi * 16) ^ swz));

    // ---- phase 2: MFMA (1,0) ----
    PH_BARRIER();
    MFMA_Q(1, 0);

    // ---- phase 3: MFMA (1,1) ----
    PH_BARRIER();
    MFMA_Q(1, 1);
  }

  if (MODE == 0) {
    // direct fp32 store: C/D layout row=(lane>>4)*4+reg, col=lane&15
#pragma unroll
    for (int mi = 0; mi < 8; ++mi)
#pragma unroll
      for (int r = 0; r < 4; ++r) {
        int row = bm0 + wr * 128 + mi * 16 + hi * 4 + r;
#pragma unroll
        for (int ni = 0; ni < 4; ++ni) {
          int col = bn0 + wc * 64 + ni * 16 + lo;
          ((float*)Cp)[(size_t)row * ldc + col] = acc[mi][ni][r];
        }
      }
  } else {
    // ---- fused epilogue: restage C-tile to LDS, RoPE q/k, emit qkv + V^T ----
    PH_BARRIER();   // all frag reads of smem done across waves
    short* Ct = (short*)smem;   // [256][256] bf16, chunk-XOR swizzled via ct_addr
#pragma unroll
    for (int mi = 0; mi < 8; ++mi)
#pragma unroll
      for (int r = 0; r < 4; ++r) {
        int row = wr * 128 + mi * 16 + hi * 4 + r;
#pragma unroll
        for (int ni = 0; ni < 4; ++ni) {
          int col = wc * 64 + ni * 16 + lo;
          *(short*)((char*)Ct + ct_addr(row, col)) = f2bf(acc[mi][ni][r]);
        }
      }
    PH_BARRIER();

    short* qkvb = (short*)Cp;
    if (bn0 < 8192) {
      // q or k block: RoPE. pair (d, d+64) within head; block spans 2 full heads.
#pragma unroll
      for (int it = 0; it < 16; ++it) {
        int idx = it * 512 + tid;
        int row = idx >> 5, c8 = idx & 31;
        int col0 = c8 * 8;
        int dloc = (bn0 + col0) & 127;       // 0..127 within head, 8-aligned
        float pos = (float)positions[bm0 + row];
        short8 o;
        if (dloc < 64) {
#pragma unroll
          for (int j = 0; j < 8; ++j) {
            int d = dloc + j;
            float inv = exp2f((float)d * -0.2076205059304570f);
            float s, c; sincosf(pos * inv, &s, &c);
            float x1 = bf2f(*(const short*)((const char*)Ct + ct_addr(row, col0 + j)));
            float x2 = bf2f(*(const short*)((const char*)Ct + ct_addr(row, col0 + j + 64)));
            o[j] = f2bf(x1 * c - x2 * s);
          }
        } else {
#pragma unroll
          for (int j = 0; j < 8; ++j) {
            int d = dloc - 64 + j;
            float inv = exp2f((float)d * -0.2076205059304570f);
            float s, c; sincosf(pos * inv, &s, &c);
            float x2 = bf2f(*(const short*)((const char*)Ct + ct_addr(row, col0 + j)));
            float x1 = bf2f(*(const short*)((const char*)Ct + ct_addr(row, col0 + j - 64)));
            o[j] = f2bf(x2 * c + x1 * s);
          }
        }
        *(short8*)(qkvb + (size_t)(bm0 + row) * QKVLD + bn0 + col0) = o;
      }
    } else {
      // V block: plain store + transposed V^T emit
#pragma unroll
      for (int it = 0; it < 16; ++it) {
        int idx = it * 512 + tid;
        int row = idx >> 5, c8 = idx & 31;
        int col0 = c8 * 8;
        short8 o;
#pragma unroll
        for (int j = 0; j < 8; ++j)
          o[j] = *(const short*)((const char*)Ct + ct_addr(row, col0 + j));
        *(short8*)(qkvb + (size_t)(bm0 + row) * QKVLD + bn0 + col0) = o;
      }
      const int b = bm0 >> 11, srow0 = bm0 & 2047;
#pragma unroll
      for (int it = 0; it < 16; ++it) {
        int idx = it * 512 + tid;
        int vcol = idx >> 5;                  // 0..255 (d-col within block)
        int s8 = (idx & 31) << 3;             // row group of 8
        int gcolv = bn0 - 8192 + vcol;        // 0..4095
        int h = gcolv >> 7, d = gcolv & 127;
        short8 o;
#pragma unroll
        for (int j = 0; j < 8; ++j)
          o[j] = *(const short*)((const char*)Ct + ct_addr(s8 + j, vcol));
        *(short8*)(Vtg + (size_t)((b * 32 + h) * 128 + d) * Sdim + srow0 + s8) = o;
      }
    }
  }
}

// ---------------- causal flash attention (dbuf K/Vt, ones-column + defer-max) ----------------
__device__ __forceinline__ void stage_kv(const short* Kb, const short* Vtb, int kv0,
                                         char* kbuf, char* vbuf, int tid, int wave) {
#pragma unroll
  for (int i = 0; i < 4; ++i) {
    int p = i * 256 + tid;            // 16B chunk id in [0,1024)
    int r = p >> 4;                   // kv row (16 chunks/row)
    int c = (p & 15) ^ (r & 7);       // swizzled chunk within row
    gload_lds16(Kb + (size_t)(kv0 + r) * QKVLD + (c << 3),
                kbuf + ((i * 256 + wave * 64) << 4));
  }
#pragma unroll
  for (int i = 0; i < 4; ++i) {
    int p = i * 256 + tid;
    int r = p >> 3;                   // d row (8 chunks/row)
    int c = (p & 7) ^ (r & 7);        // swizzled chunk within row
    gload_lds16(Vtb + (size_t)r * Sdim + kv0 + (c << 3),
                vbuf + ((i * 256 + wave * 64) << 4));
  }
}

__global__ __launch_bounds__(256, 2) void k_attn(short* __restrict__ qkv,
                                                 const short* __restrict__ Vt) {
  __shared__ __align__(16) char smem[81920];
  const int tid  = threadIdx.x;
  const int lane = tid & 63;
  const int wave = tid >> 6;
  const int lo = lane & 15, hi = lane >> 4;

  const int bid = blockIdx.x;
  const int lid = (bid & 7) * 128 + (bid >> 3);
  const int bh = lid >> 4;
  const int qt = 15 - (lid & 15);     // heavy tiles first
  const int b = bh >> 5, h = bh & 31;
  const int q0 = qt << 7;

  short* base = qkv + (size_t)b * Sdim * QKVLD;
  const short* Qb = base + h * Dh;
  const short* Kb = base + Hdim + h * Dh;
  const short* Vtb = Vt + (size_t)(b * 32 + h) * 128 * Sdim;
  const int qrow0 = q0 + wave * 32;

  short* Pw = (short*)(smem + 65536 + wave * 4096);

  short8 qf[2][4];
#pragma unroll
  for (int mi = 0; mi < 2; ++mi)
#pragma unroll
    for (int ks = 0; ks < 4; ++ks)
      qf[mi][ks] = *(const short8*)(Qb + (size_t)(qrow0 + mi * 16 + lo) * QKVLD + ks * 32 + hi * 8);

  f32x4 acc_o[2][9];
  float m_run[2][4];
#pragma unroll
  for (int mi = 0; mi < 2; ++mi) {
#pragma unroll
    for (int nf = 0; nf < 9; ++nf) acc_o[mi][nf] = (f32x4){0.f, 0.f, 0.f, 0.f};
#pragma unroll
    for (int r = 0; r < 4; ++r) m_run[mi][r] = -1e30f;
  }

  short8 vones;
#pragma unroll
  for (int j = 0; j < 8; ++j) vones[j] = (short)0x3F80;  // bf16 1.0

  const float SEXP = 0.088388347648318447f * 1.4426950408889634f;  // scale*log2e
  const int nkv = (q0 + 128) >> 6;
  const int swz = (lo & 7) << 4;

  stage_kv(Kb, Vtb, 0, smem, smem + 16384, tid, wave);
  __syncthreads();

  int cur = 0;
  for (int kvt = 0; kvt < nkv; ++kvt) {
    const int kv0 = kvt << 6;
    if (kvt + 1 < nkv)
      stage_kv(Kb, Vtb, kv0 + 64, smem + (cur ^ 1) * 32768,
               smem + (cur ^ 1) * 32768 + 16384, tid, wave);

    if (kv0 <= qrow0 + 31) {
      const char* kl = smem + cur * 32768;
      const char* vl = smem + cur * 32768 + 16384;

      f32x4 accs[2][4];
#pragma unroll
      for (int mi = 0; mi < 2; ++mi)
#pragma unroll
        for (int nf = 0; nf < 4; ++nf) accs[mi][nf] = (f32x4){0.f, 0.f, 0.f, 0.f};
#pragma unroll
      for (int ks = 0; ks < 4; ++ks) {
        short8 kf[4];
#pragma unroll
        for (int nf = 0; nf < 4; ++nf) {
          int r = nf * 16 + lo;
          kf[nf] = *(const short8*)(kl + r * 256 + ((ks * 64 + hi * 16) ^ swz));
        }
        __builtin_amdgcn_s_setprio(1);
#pragma unroll
        for (int mi = 0; mi < 2; ++mi)
#pragma unroll
          for (int nf = 0; nf < 4; ++nf)
            accs[mi][nf] = __builtin_amdgcn_mfma_f32_16x16x32_bf16(qf[mi][ks], kf[nf], accs[mi][nf], 0, 0, 0);
        __builtin_amdgcn_s_setprio(0);
      }

      const bool needmask = (kv0 + 63 > qrow0);
      float pmax[2][4];
      bool okall = true;
#pragma unroll
      for (int mi = 0; mi < 2; ++mi) {
#pragma unroll
        for (int r = 0; r < 4; ++r) {
          const int qrow = qrow0 + mi * 16 + hi * 4 + r;
          float tmax = -1e30f;
#pragma unroll
          for (int nf = 0; nf < 4; ++nf) {
            float v = accs[mi][nf][r] * SEXP;
            if (needmask) {
              int col = kv0 + nf * 16 + lo;
              v = (col <= qrow) ? v : -1e30f;
            }
            accs[mi][nf][r] = v;
            tmax = fmaxf(tmax, v);
          }
#pragma unroll
          for (int off = 1; off < 16; off <<= 1)
            tmax = fmaxf(tmax, __shfl_xor(tmax, off, 64));
          pmax[mi][r] = tmax;
          okall = okall && (tmax <= m_run[mi][r] + 8.0f);
        }
      }
      if (!__all(okall)) {
#pragma unroll
        for (int mi = 0; mi < 2; ++mi)
#pragma unroll
          for (int r = 0; r < 4; ++r) {
            float mnew = fmaxf(m_run[mi][r], pmax[mi][r]);
            float alpha = exp2f(m_run[mi][r] - mnew);
            m_run[mi][r] = mnew;
#pragma unroll
            for (int nf = 0; nf < 9; ++nf) acc_o[mi][nf][r] *= alpha;
          }
      }
#pragma unroll
      for (int mi = 0; mi < 2; ++mi)
#pragma unroll
        for (int r = 0; r < 4; ++r) {
          const int prow = mi * 16 + hi * 4 + r;
          const int psw = prow & 7;
#pragma unroll
          for (int nf = 0; nf < 4; ++nf) {
            float p = exp2f(accs[mi][nf][r] - m_run[mi][r]);
            int col = nf * 16 + lo;
            Pw[(prow << 6) + (((col >> 3) ^ psw) << 3) + (col & 7)] = f2bf(p);
          }
        }

#pragma unroll
      for (int ks = 0; ks < 2; ++ks) {
        short8 pf[2];
#pragma unroll
        for (int mi = 0; mi < 2; ++mi) {
          int prow = mi * 16 + lo;
          pf[mi] = *(const short8*)((const char*)Pw + prow * 128 + (((ks * 4 + hi) ^ (prow & 7)) << 4));
        }
        __builtin_amdgcn_s_setprio(1);
#pragma unroll
        for (int nf = 0; nf < 9; ++nf) {
          short8 vf;
          if (nf < 8) {
            int row = nf * 16 + lo;
            vf = *(const short8*)(vl + row * 128 + ((ks * 64 + hi * 16) ^ swz));
          } else {
            vf = vones;
          }
#pragma unroll
          for (int mi = 0; mi < 2; ++mi)
            acc_o[mi][nf] = __builtin_amdgcn_mfma_f32_16x16x32_bf16(pf[mi], vf, acc_o[mi][nf], 0, 0, 0);
        }
        __builtin_amdgcn_s_setprio(0);
      }
    }

    __syncthreads();
    cur ^= 1;
  }

  short* Osm = (short*)smem;   // [128][128]
#pragma unroll
  for (int mi = 0; mi < 2; ++mi)
#pragma unroll
    for (int r = 0; r < 4; ++r) {
      float inv = 1.0f / acc_o[mi][8][r];
      int row = wave * 32 + mi * 16 + hi * 4 + r;
#pragma unroll
      for (int nf = 0; nf < 8; ++nf)
        Osm[row * 128 + nf * 16 + lo] = f2bf(acc_o[mi][nf][r] * inv);
    }
  __syncthreads();
  short* Ob = base + h * Dh;
#pragma unroll
  for (int it = 0; it < 8; ++it) {
    int chunk = it * 256 + tid;
    int row = chunk >> 4, c8 = chunk & 15;
    *(short8*)(Ob + (size_t)(q0 + row) * QKVLD + c8 * 8) =
        *(const short8*)(Osm + row * 128 + c8 * 8);
  }
}

extern "C" void kernel_launch(void* const* d_in, const int* in_sizes, int n_in,
                              void* d_out, int out_size, void* d_ws, size_t ws_size,
                              hipStream_t stream) {
  const int*   positions = (const int*)d_in[0];
  const float* hidden    = (const float*)d_in[1];
  const float* w_pack    = (const float*)d_in[2];
  const float* w_o       = (const float*)d_in[3];
  float* out = (float*)d_out;

  char* ws = (char*)d_ws;
  short* Wpt  = (short*)ws;                                 // w_pack^T bf16 [12288][4096]
  short* qkvb = (short*)(ws + (size_t)12288 * 4096 * 2);    // qkv bf16 [4096][12288]
  short* Wot  = (short*)ws;                                 // w_o^T bf16 (reuses Wpt region)
  short* Hbf  = (short*)d_out;                              // hidden bf16 (d_out front 32MB)
  short* Vtg  = (short*)((char*)d_out + ((size_t)32 << 20)); // V^T bf16 (d_out back 32MB)

  // 1. hidden fp32 -> bf16 (dead after GEMM1)
  k_cvt<<<8192, 256, 0, stream>>>(hidden, Hbf, 4096 * 4096 / 8);
  // 2. w_pack^T bf16 (vectorized 64x64 transpose)
  k_tcvt64<<<dim3(12288 / 64, 4096 / 64), 256, 0, stream>>>(w_pack, Wpt, 4096, 12288);
  // 3. qkv = hidden @ w_pack, fused RoPE + V^T emit (grid 16 x 48 = 768, %8==0)
  k_gemm256<1><<<dim3(768), 512, 0, stream>>>(Hbf, 4096, Wpt, 4096, qkvb, QKVLD, 12288, 4096,
                                              positions, Vtg);
  // 4. attention; O overwrites q region of qkv
  k_attn<<<dim3(1024), 256, 0, stream>>>(qkvb, Vtg);
  // 5. w_o^T bf16 (Wpt region dead)
  k_tcvt64<<<dim3(4096 / 64, 4096 / 64), 256, 0, stream>>>(w_o, Wot, 4096, 4096);
  // 6. out = O @ w_o (fp32), overwrites all of d_out (grid 16 x 16 = 256)
  k_gemm256<0><<<dim3(256), 512, 0, stream>>>(qkvb, QKVLD, Wot, 4096, out, 4096, 4096, 4096,
                                              nullptr, nullptr);
}

// Round 9
// 760.223 us; speedup vs baseline: 1.0389x; 1.0389x over previous
//
#include <hip/hip_runtime.h>

// Problem constants
#define Sdim   2048
#define Hdim   4096
#define NHEADS 32
#define Dh     128
#define Mrows  4096      // B*S
#define QKVLD  12288     // 3*H

typedef __attribute__((ext_vector_type(8))) short short8;
typedef __attribute__((ext_vector_type(4))) float f32x4;
typedef __attribute__((ext_vector_type(4))) float float4v;

__device__ __forceinline__ short f2bf(float f) {
  union { float f; unsigned u; } x; x.f = f;
  unsigned r = x.u + 0x7fffu + ((x.u >> 16) & 1u);  // RNE
  return (short)(r >> 16);
}
__device__ __forceinline__ float bf2f(short s) {
  union { unsigned u; float f; } x; x.u = ((unsigned)(unsigned short)s) << 16;
  return x.f;
}

__device__ __forceinline__ void gload_lds16(const void* g, void* l) {
  __builtin_amdgcn_global_load_lds(
      (const __attribute__((address_space(1))) void*)g,
      (__attribute__((address_space(3))) void*)l, 16, 0, 0);
}

// ---------------- fp32 -> bf16 convert (8 elems/thread) ----------------
__global__ void k_cvt(const float* __restrict__ src, short* __restrict__ dst, int n8) {
  int idx = blockIdx.x * blockDim.x + threadIdx.x;
  if (idx >= n8) return;
  const float4v* s = (const float4v*)src + (size_t)idx * 2;
  float4v a = s[0], b = s[1];
  short8 o;
  o[0] = f2bf(a.x); o[1] = f2bf(a.y); o[2] = f2bf(a.z); o[3] = f2bf(a.w);
  o[4] = f2bf(b.x); o[5] = f2bf(b.y); o[6] = f2bf(b.z); o[7] = f2bf(b.w);
  *((short8*)dst + idx) = o;
}

// ---- transpose + convert, vectorized both sides: dst[C][R] bf16 = src[R][C] f32 ----
__global__ void k_tcvt64(const float* __restrict__ src, short* __restrict__ dst,
                         int R, int C) {
  __shared__ float t[64][65];
  const int tid = threadIdx.x;          // 256
  const int r0 = blockIdx.y * 64, c0 = blockIdx.x * 64;
  const int ir = tid >> 4, ic = (tid & 15) << 2;
#pragma unroll
  for (int p = 0; p < 4; ++p) {
    const float4v v = *(const float4v*)(src + (size_t)(r0 + p * 16 + ir) * C + c0 + ic);
    t[p * 16 + ir][ic] = v.x; t[p * 16 + ir][ic + 1] = v.y;
    t[p * 16 + ir][ic + 2] = v.z; t[p * 16 + ir][ic + 3] = v.w;
  }
  __syncthreads();
  const int oc = tid >> 3, orr = (tid & 7) << 3;
#pragma unroll
  for (int p = 0; p < 2; ++p) {
    int c = p * 32 + oc;
    short8 o;
#pragma unroll
    for (int j = 0; j < 8; ++j) o[j] = f2bf(t[orr + j][c]);
    *(short8*)(dst + (size_t)(c0 + c) * R + r0 + orr) = o;
  }
}

// ------- V transpose, vectorized: Vt[(b*32+h)*128+d][s] = qkv[b*2048+s][8192+hc] -------
// 64x64 bf16 tile; short8 global loads/stores; LDS chunk-XOR swizzle with FULL-row term
// (c8 ^= (row ^ row>>3)&7) so the transposed scalar reads land 2 lanes/bank (free).
__global__ void k_vt64(const short* __restrict__ qkv, short* __restrict__ vt) {
  __shared__ short tile[4096];  // [64 s][64 d] swizzled
  const int tid = threadIdx.x;          // 256
  const int c0 = blockIdx.x * 64;       // d-col base (0..4095)
  const int s0 = blockIdx.y * 64;       // token base within batch
  const int b  = blockIdx.z;
#pragma unroll
  for (int j = 0; j < 2; ++j) {
    int chunk = j * 256 + tid;
    int row = chunk >> 3, c8 = chunk & 7;
    short8 v = *(const short8*)(qkv + (size_t)(b * 2048 + s0 + row) * QKVLD + 8192 + c0 + c8 * 8);
    int sw = c8 ^ ((row ^ (row >> 3)) & 7);
    *(short8*)((char*)tile + row * 128 + sw * 16) = v;
  }
  __syncthreads();
#pragma unroll
  for (int j = 0; j < 2; ++j) {
    int chunk = j * 256 + tid;
    int d = chunk >> 3, s8 = (chunk & 7) << 3;
    short8 o;
#pragma unroll
    for (int j2 = 0; j2 < 8; ++j2) {
      int s = s8 + j2;
      int sw = ((d >> 3) ^ ((s ^ (s >> 3)) & 7));
      o[j2] = *(const short*)((const char*)tile + s * 128 + sw * 16 + (d & 7) * 2);
    }
    *(short8*)(vt + (size_t)(b * 4096 + c0 + d) * Sdim + s0 + s8) = o;
  }
}

// ============ 256x256-tile bf16 GEMM, 8 waves, 4 phases/K-tile, counted vmcnt ============
__device__ __forceinline__ void stage_half256(const short* G, int ld, int row0, int kcol,
                                              char* lds, int tid) {
#pragma unroll
  for (int j = 0; j < 2; ++j) {
    int p = j * 512 + tid;            // 16B chunk id in [0,1024): 8 chunks per 64-col row
    int r = p >> 3;
    int c = ((p & 7) ^ (r & 7)) << 3; // swizzled source column (elements)
    gload_lds16(G + (size_t)(row0 + r) * ld + kcol + c,
                lds + ((j * 512 + (tid & 448)) << 4));
  }
}

#define MFMA_Q(qm, qn)                                                                   \
  do {                                                                                   \
    __builtin_amdgcn_s_setprio(1);                                                       \
    _Pragma("unroll")                                                                    \
    for (int m4 = 0; m4 < 4; ++m4)                                                       \
      _Pragma("unroll")                                                                  \
      for (int n2 = 0; n2 < 2; ++n2) {                                                   \
        acc[(qm)*4+m4][(qn)*2+n2] = __builtin_amdgcn_mfma_f32_16x16x32_bf16(             \
            av[m4][0], bv[(qn)*2+n2][0], acc[(qm)*4+m4][(qn)*2+n2], 0, 0, 0);            \
        acc[(qm)*4+m4][(qn)*2+n2] = __builtin_amdgcn_mfma_f32_16x16x32_bf16(             \
            av[m4][1], bv[(qn)*2+n2][1], acc[(qm)*4+m4][(qn)*2+n2], 0, 0, 0);            \
      }                                                                                  \
    __builtin_amdgcn_s_setprio(0);                                                       \
  } while (0)

#define PH_BARRIER()                    \
  do {                                  \
    __builtin_amdgcn_s_barrier();       \
    __builtin_amdgcn_sched_barrier(0);  \
  } while (0)

template<bool C_F32>
__global__ __launch_bounds__(512, 2) void k_gemm256(const short* __restrict__ A, int lda,
                                                    const short* __restrict__ Bt, int ldb,
                                                    void* __restrict__ Cp, int ldc,
                                                    int Ndim, int Kdim) {
  __shared__ __align__(16) char smem[131072];
  const int tid  = threadIdx.x;
  const int lane = tid & 63;
  const int wave = tid >> 6;
  const int lo = lane & 15, hi = lane >> 4;
  const int wr = wave >> 2, wc = wave & 3;   // 2M x 4N waves; per-wave out 128x64

  // T1: XCD-aware bijective block swizzle (grid % 8 == 0 for all our calls)
  const int nblk = gridDim.x;
  const int lid = (blockIdx.x & 7) * (nblk >> 3) + (blockIdx.x >> 3);
  const int nbn = Ndim >> 8;
  const int bm0 = (lid / nbn) << 8;
  const int bn0 = (lid % nbn) << 8;

  f32x4 acc[8][4];
#pragma unroll
  for (int i = 0; i < 8; ++i)
#pragma unroll
    for (int j = 0; j < 4; ++j) acc[i][j] = (f32x4){0.f, 0.f, 0.f, 0.f};

  short8 av[4][2], bv[4][2];
  const int swz = (lo & 7) << 4;
  const int brow = (wc & 1) * 64;

  // prologue: K-tile 0 -> slot 0
  stage_half256(Bt, ldb, bn0,       0, smem + 32768,         tid);
  stage_half256(Bt, ldb, bn0 + 128, 0, smem + 32768 + 16384, tid);
  stage_half256(A,  lda, bm0,       0, smem,                 tid);
  stage_half256(A,  lda, bm0 + 128, 0, smem + 16384,         tid);

  const int NK = Kdim >> 6;
  for (int kt = 0; kt < NK; ++kt) {
    const int cur = kt & 1;
    const char* Ab = smem + cur * 65536 + wr * 16384;                 // wave's A half
    const char* Bb = smem + cur * 65536 + 32768 + (wc >> 1) * 16384;  // wave's B half
    char* nA = smem + (cur ^ 1) * 65536;
    char* nB = nA + 32768;
    const int kc = (kt + 1) << 6;
    const bool pf = (kt + 1 < NK);

    // ---- phase 0: stage B'h0+B'h1; counted drain; read A[0-3],B[0-1]; MFMA (0,0) ----
    if (pf) {
      stage_half256(Bt, ldb, bn0,       kc, nB,         tid);
      stage_half256(Bt, ldb, bn0 + 128, kc, nB + 16384, tid);
      asm volatile("s_waitcnt vmcnt(4)" ::: "memory");   // prev 8 landed; own 4 in flight
    } else {
      asm volatile("s_waitcnt vmcnt(0)" ::: "memory");   // final tile: full drain
    }
    PH_BARRIER();   // after this, slot cur is fully landed for ALL waves
#pragma unroll
    for (int m4 = 0; m4 < 4; ++m4)
#pragma unroll
      for (int ks = 0; ks < 2; ++ks)
        av[m4][ks] = *(const short8*)(Ab + (m4 * 16 + lo) * 128 + ((ks * 64 + hi * 16) ^ swz));
#pragma unroll
    for (int ni = 0; ni < 2; ++ni)
#pragma unroll
      for (int ks = 0; ks < 2; ++ks)
        bv[ni][ks] = *(const short8*)(Bb + (brow + ni * 16 + lo) * 128 + ((ks * 64 + hi * 16) ^ swz));
    MFMA_Q(0, 0);
    // hoisted reads for phase 1 (slot cur is landed)
#pragma unroll
    for (int ni = 2; ni < 4; ++ni)
#pragma unroll
      for (int ks = 0; ks < 2; ++ks)
        bv[ni][ks] = *(const short8*)(Bb + (brow + ni * 16 + lo) * 128 + ((ks * 64 + hi * 16) ^ swz));

    // ---- phase 1: stage A'h0+A'h1; MFMA (0,1); hoist A-rows 64-127 reads ----
    if (pf) {
      stage_half256(A, lda, bm0,       kc, nA,         tid);
      stage_half256(A, lda, bm0 + 128, kc, nA + 16384, tid);
    }
    PH_BARRIER();
    MFMA_Q(0, 1);
#pragma unroll
    for (int m4 = 0; m4 < 4; ++m4)
#pragma unroll
      for (int ks = 0; ks < 2; ++ks)
        av[m4][ks] = *(const short8*)(Ab + ((64 + m4 * 16 + lo) * 128) + ((ks * 64 + hi * 16) ^ swz));

    // ---- phase 2: MFMA (1,0) ----
    PH_BARRIER();
    MFMA_Q(1, 0);

    // ---- phase 3: MFMA (1,1) ----
    PH_BARRIER();
    MFMA_Q(1, 1);
  }

  // epilogue: C/D layout row=(lane>>4)*4+reg, col=lane&15
#pragma unroll
  for (int mi = 0; mi < 8; ++mi)
#pragma unroll
    for (int r = 0; r < 4; ++r) {
      int row = bm0 + wr * 128 + mi * 16 + hi * 4 + r;
#pragma unroll
      for (int ni = 0; ni < 4; ++ni) {
        int col = bn0 + wc * 64 + ni * 16 + lo;
        if (C_F32) ((float*)Cp)[(size_t)row * ldc + col] = acc[mi][ni][r];
        else       ((short*)Cp)[(size_t)row * ldc + col] = f2bf(acc[mi][ni][r]);
      }
    }
}

// ------------- RoPE in-place, vectorized: 8 consecutive d per thread (short8 x4) -------------
__global__ void k_rope8(short* qkv, const int* __restrict__ positions) {
  int idx = blockIdx.x * 256 + threadIdx.x;   // (row, h, t): 4096*32*8 threads
  int t = idx & 7;
  int h = (idx >> 3) & 31;
  int row = idx >> 8;
  float pos = (float)positions[row];
  size_t o = (size_t)row * QKVLD + h * 128 + t * 8;
  short8 q1 = *(short8*)(qkv + o),        q2 = *(short8*)(qkv + o + 64);
  short8 k1 = *(short8*)(qkv + o + 4096), k2 = *(short8*)(qkv + o + 4160);
#pragma unroll
  for (int j = 0; j < 8; ++j) {
    int d = t * 8 + j;
    float inv = exp2f((float)d * -0.2076205059304570f);
    float ang = pos * inv, s, c;
    sincosf(ang, &s, &c);
    float a1 = bf2f(q1[j]), a2 = bf2f(q2[j]);
    q1[j] = f2bf(a1 * c - a2 * s); q2[j] = f2bf(a2 * c + a1 * s);
    float b1 = bf2f(k1[j]), b2 = bf2f(k2[j]);
    k1[j] = f2bf(b1 * c - b2 * s); k2[j] = f2bf(b2 * c + b1 * s);
  }
  *(short8*)(qkv + o) = q1;        *(short8*)(qkv + o + 64) = q2;
  *(short8*)(qkv + o + 4096) = k1; *(short8*)(qkv + o + 4160) = k2;
}

// ---------------- causal flash attention (dbuf K/Vt, ones-column + defer-max) ----------------
__device__ __forceinline__ void stage_kv(const short* Kb, const short* Vtb, int kv0,
                                         char* kbuf, char* vbuf, int tid, int wave) {
#pragma unroll
  for (int i = 0; i < 4; ++i) {
    int p = i * 256 + tid;            // 16B chunk id in [0,1024)
    int r = p >> 4;                   // kv row (16 chunks/row)
    int c = (p & 15) ^ (r & 7);       // swizzled chunk within row
    gload_lds16(Kb + (size_t)(kv0 + r) * QKVLD + (c << 3),
                kbuf + ((i * 256 + wave * 64) << 4));
  }
#pragma unroll
  for (int i = 0; i < 4; ++i) {
    int p = i * 256 + tid;
    int r = p >> 3;                   // d row (8 chunks/row)
    int c = (p & 7) ^ (r & 7);        // swizzled chunk within row
    gload_lds16(Vtb + (size_t)r * Sdim + kv0 + (c << 3),
                vbuf + ((i * 256 + wave * 64) << 4));
  }
}

__global__ __launch_bounds__(256, 2) void k_attn(short* __restrict__ qkv,
                                                 const short* __restrict__ Vt) {
  __shared__ __align__(16) char smem[81920];
  const int tid  = threadIdx.x;
  const int lane = tid & 63;
  const int wave = tid >> 6;
  const int lo = lane & 15, hi = lane >> 4;

  const int bid = blockIdx.x;
  const int lid = (bid & 7) * 128 + (bid >> 3);
  const int bh = lid >> 4;
  const int qt = 15 - (lid & 15);     // heavy tiles first
  const int b = bh >> 5, h = bh & 31;
  const int q0 = qt << 7;

  short* base = qkv + (size_t)b * Sdim * QKVLD;
  const short* Qb = base + h * Dh;
  const short* Kb = base + Hdim + h * Dh;
  const short* Vtb = Vt + (size_t)(b * 32 + h) * 128 * Sdim;
  const int qrow0 = q0 + wave * 32;

  short* Pw = (short*)(smem + 65536 + wave * 4096);

  short8 qf[2][4];
#pragma unroll
  for (int mi = 0; mi < 2; ++mi)
#pragma unroll
    for (int ks = 0; ks < 4; ++ks)
      qf[mi][ks] = *(const short8*)(Qb + (size_t)(qrow0 + mi * 16 + lo) * QKVLD + ks * 32 + hi * 8);

  f32x4 acc_o[2][9];
  float m_run[2][4];
#pragma unroll
  for (int mi = 0; mi < 2; ++mi) {
#pragma unroll
    for (int nf = 0; nf < 9; ++nf) acc_o[mi][nf] = (f32x4){0.f, 0.f, 0.f, 0.f};
#pragma unroll
    for (int r = 0; r < 4; ++r) m_run[mi][r] = -1e30f;
  }

  short8 vones;
#pragma unroll
  for (int j = 0; j < 8; ++j) vones[j] = (short)0x3F80;  // bf16 1.0

  const float SEXP = 0.088388347648318447f * 1.4426950408889634f;  // scale*log2e
  const int nkv = (q0 + 128) >> 6;
  const int swz = (lo & 7) << 4;

  stage_kv(Kb, Vtb, 0, smem, smem + 16384, tid, wave);
  __syncthreads();

  int cur = 0;
  for (int kvt = 0; kvt < nkv; ++kvt) {
    const int kv0 = kvt << 6;
    if (kvt + 1 < nkv)
      stage_kv(Kb, Vtb, kv0 + 64, smem + (cur ^ 1) * 32768,
               smem + (cur ^ 1) * 32768 + 16384, tid, wave);

    if (kv0 <= qrow0 + 31) {
      const char* kl = smem + cur * 32768;
      const char* vl = smem + cur * 32768 + 16384;

      f32x4 accs[2][4];
#pragma unroll
      for (int mi = 0; mi < 2; ++mi)
#pragma unroll
        for (int nf = 0; nf < 4; ++nf) accs[mi][nf] = (f32x4){0.f, 0.f, 0.f, 0.f};
#pragma unroll
      for (int ks = 0; ks < 4; ++ks) {
        short8 kf[4];
#pragma unroll
        for (int nf = 0; nf < 4; ++nf) {
          int r = nf * 16 + lo;
          kf[nf] = *(const short8*)(kl + r * 256 + ((ks * 64 + hi * 16) ^ swz));
        }
        __builtin_amdgcn_s_setprio(1);
#pragma unroll
        for (int mi = 0; mi < 2; ++mi)
#pragma unroll
          for (int nf = 0; nf < 4; ++nf)
            accs[mi][nf] = __builtin_amdgcn_mfma_f32_16x16x32_bf16(qf[mi][ks], kf[nf], accs[mi][nf], 0, 0, 0);
        __builtin_amdgcn_s_setprio(0);
      }

      const bool needmask = (kv0 + 63 > qrow0);
      float pmax[2][4];
      bool okall = true;
#pragma unroll
      for (int mi = 0; mi < 2; ++mi) {
#pragma unroll
        for (int r = 0; r < 4; ++r) {
          const int qrow = qrow0 + mi * 16 + hi * 4 + r;
          float tmax = -1e30f;
#pragma unroll
          for (int nf = 0; nf < 4; ++nf) {
            float v = accs[mi][nf][r] * SEXP;
            if (needmask) {
              int col = kv0 + nf * 16 + lo;
              v = (col <= qrow) ? v : -1e30f;
            }
            accs[mi][nf][r] = v;
            tmax = fmaxf(tmax, v);
          }
#pragma unroll
          for (int off = 1; off < 16; off <<= 1)
            tmax = fmaxf(tmax, __shfl_xor(tmax, off, 64));
          pmax[mi][r] = tmax;
          okall = okall && (tmax <= m_run[mi][r] + 8.0f);
        }
      }
      if (!__all(okall)) {
#pragma unroll
        for (int mi = 0; mi < 2; ++mi)
#pragma unroll
          for (int r = 0; r < 4; ++r) {
            float mnew = fmaxf(m_run[mi][r], pmax[mi][r]);
            float alpha = exp2f(m_run[mi][r] - mnew);
            m_run[mi][r] = mnew;
#pragma unroll
            for (int nf = 0; nf < 9; ++nf) acc_o[mi][nf][r] *= alpha;
          }
      }
#pragma unroll
      for (int mi = 0; mi < 2; ++mi)
#pragma unroll
        for (int r = 0; r < 4; ++r) {
          const int prow = mi * 16 + hi * 4 + r;
          const int psw = prow & 7;
#pragma unroll
          for (int nf = 0; nf < 4; ++nf) {
            float p = exp2f(accs[mi][nf][r] - m_run[mi][r]);
            int col = nf * 16 + lo;
            Pw[(prow << 6) + (((col >> 3) ^ psw) << 3) + (col & 7)] = f2bf(p);
          }
        }

#pragma unroll
      for (int ks = 0; ks < 2; ++ks) {
        short8 pf[2];
#pragma unroll
        for (int mi = 0; mi < 2; ++mi) {
          int prow = mi * 16 + lo;
          pf[mi] = *(const short8*)((const char*)Pw + prow * 128 + (((ks * 4 + hi) ^ (prow & 7)) << 4));
        }
        __builtin_amdgcn_s_setprio(1);
#pragma unroll
        for (int nf = 0; nf < 9; ++nf) {
          short8 vf;
          if (nf < 8) {
            int row = nf * 16 + lo;
            vf = *(const short8*)(vl + row * 128 + ((ks * 64 + hi * 16) ^ swz));
          } else {
            vf = vones;
          }
#pragma unroll
          for (int mi = 0; mi < 2; ++mi)
            acc_o[mi][nf] = __builtin_amdgcn_mfma_f32_16x16x32_bf16(pf[mi], vf, acc_o[mi][nf], 0, 0, 0);
        }
        __builtin_amdgcn_s_setprio(0);
      }
    }

    __syncthreads();
    cur ^= 1;
  }

  short* Osm = (short*)smem;   // [128][128]
#pragma unroll
  for (int mi = 0; mi < 2; ++mi)
#pragma unroll
    for (int r = 0; r < 4; ++r) {
      float inv = 1.0f / acc_o[mi][8][r];
      int row = wave * 32 + mi * 16 + hi * 4 + r;
#pragma unroll
      for (int nf = 0; nf < 8; ++nf)
        Osm[row * 128 + nf * 16 + lo] = f2bf(acc_o[mi][nf][r] * inv);
    }
  __syncthreads();
  short* Ob = base + h * Dh;
#pragma unroll
  for (int it = 0; it < 8; ++it) {
    int chunk = it * 256 + tid;
    int row = chunk >> 4, c8 = chunk & 15;
    *(short8*)(Ob + (size_t)(q0 + row) * QKVLD + c8 * 8) =
        *(const short8*)(Osm + row * 128 + c8 * 8);
  }
}

extern "C" void kernel_launch(void* const* d_in, const int* in_sizes, int n_in,
                              void* d_out, int out_size, void* d_ws, size_t ws_size,
                              hipStream_t stream) {
  const int*   positions = (const int*)d_in[0];
  const float* hidden    = (const float*)d_in[1];
  const float* w_pack    = (const float*)d_in[2];
  const float* w_o       = (const float*)d_in[3];
  float* out = (float*)d_out;

  char* ws = (char*)d_ws;
  short* Wpt  = (short*)ws;                                 // w_pack^T bf16 [12288][4096]
  short* qkvb = (short*)(ws + (size_t)12288 * 4096 * 2);    // qkv bf16 [4096][12288]
  short* Wot  = (short*)ws;                                 // w_o^T bf16 (reuses Wpt region)
  short* Hbf  = (short*)d_out;                              // hidden bf16 (d_out front 32MB)
  short* Vtg  = (short*)((char*)d_out + ((size_t)32 << 20)); // V^T bf16 (d_out back 32MB)

  // 1. hidden fp32 -> bf16 (dead after GEMM1)
  k_cvt<<<8192, 256, 0, stream>>>(hidden, Hbf, 4096 * 4096 / 8);
  // 2. w_pack^T bf16 (vectorized 64x64 transpose)
  k_tcvt64<<<dim3(12288 / 64, 4096 / 64), 256, 0, stream>>>(w_pack, Wpt, 4096, 12288);
  // 3. qkv = hidden @ w_pack  (256^2 tiles: grid 16 x 48 = 768, %8==0)
  k_gemm256<false><<<dim3(768), 512, 0, stream>>>(Hbf, 4096, Wpt, 4096, qkvb, QKVLD, 12288, 4096);
  // 4. RoPE on q,k in place (vectorized)
  k_rope8<<<4096, 256, 0, stream>>>(qkvb, positions);
  // 5. V^T into d_out back half (vectorized 64x64 transpose)
  k_vt64<<<dim3(64, 32, 2), 256, 0, stream>>>(qkvb, Vtg);
  // 6. attention; O overwrites q region of qkv
  k_attn<<<dim3(1024), 256, 0, stream>>>(qkvb, Vtg);
  // 7. w_o^T bf16 (Wpt region dead)
  k_tcvt64<<<dim3(4096 / 64, 4096 / 64), 256, 0, stream>>>(w_o, Wot, 4096, 4096);
  // 8. out = O @ w_o (fp32), overwrites all of d_out (grid 16 x 16 = 256)
  k_gemm256<true><<<dim3(256), 512, 0, stream>>>(qkvb, QKVLD, Wot, 4096, out, 4096, 4096, 4096);
}